// Round 1
// baseline (380.716 us; speedup 1.0000x reference)
//
#include <hip/hip_runtime.h>

// Problem constants (fixed by reference setup_inputs)
#define NPARTS 17
#define TAGDIM 1
#define B_ 32
#define S_ 4
#define M_ 30
#define HW_ 16384            // 128*128
#define C_ 34                // (1+TAGDIM)*NPARTS
#define TAG_W 0.001f
#define HM_W 1.0f

// det region per (b,s): NPARTS*HW floats
#define DET_PER_BS (NPARTS * HW_)            // 278528
#define DET_TOTAL  ((long)B_ * S_ * DET_PER_BS)  // 35,651,584
#define NVEC       (DET_TOTAL / 4)           // 8,912,896 float4s
#define VPBS       (DET_PER_BS / 4)          // 69632 vec4 per (b,s)
#define HV         (HW_ / 4)                 // 4096 vec4 per image plane
#define TAG_TOTAL  (B_ * S_ * M_ * NPARTS)   // 65280

__global__ __launch_bounds__(256) void loss_fused_kernel(
    const float* __restrict__ preds,      // (B,S,34,H,W)
    const float* __restrict__ masks,      // (B,H,W)
    const int*   __restrict__ kp_idx,     // (B,M,17)
    const float* __restrict__ kp_vis,     // (B,M,17)
    const float* __restrict__ gt_tags,    // (B,1,M,17)
    const float* __restrict__ heatmaps,   // (B,17,H,W)
    float* __restrict__ out)
{
    const float4* __restrict__ preds4 = (const float4*)preds;
    const float4* __restrict__ masks4 = (const float4*)masks;
    const float4* __restrict__ heat4  = (const float4*)heatmaps;

    const int tid = blockIdx.x * blockDim.x + threadIdx.x;
    const int nthreads = gridDim.x * blockDim.x;

    // ---- det loss: sum over (b,s,c<17,h,w) of (pred-hm)^2 * mask ----
    float det_acc = 0.f;
    for (long v = tid; v < NVEC; v += nthreads) {
        int bs = (int)(v / VPBS);            // which (b,s) block
        int wv = (int)(v - (long)bs * VPBS); // vec index inside det region
        int b  = bs >> 2;                    // S_ == 4
        float4 p = preds4[v + (long)bs * VPBS];   // skip tag half of earlier blocks
        float4 h = heat4[(long)b * VPBS + wv];
        float4 m = masks4[b * HV + (wv & (HV - 1))];
        float dx = p.x - h.x, dy = p.y - h.y, dz = p.z - h.z, dw = p.w - h.w;
        det_acc += dx * dx * m.x + dy * dy * m.y + dz * dz * m.z + dw * dw * m.w;
    }

    // ---- tag loss: gather 65280 elements ----
    float tag_acc = 0.f;
    for (int t = tid; t < TAG_TOTAL; t += nthreads) {
        int bs = t / (M_ * NPARTS);
        int mp = t - bs * (M_ * NPARTS);
        int b  = bs >> 2;
        int gidx = b * (M_ * NPARTS) + mp;
        int l   = kp_idx[gidx];                       // [0, 17*HW)
        float vis = kp_vis[gidx];
        float gt  = gt_tags[gidx];                    // TAGDIM==1 -> flat (B,M,P)
        // tags flat for (b,s): preds offset ((bs*34)+17)*HW + l
        float pt = preds[((long)bs * C_ + NPARTS) * HW_ + l];
        float d = pt - gt;
        tag_acc += d * d * vis;
    }

    // combined, pre-scaled
    const float det_scale = HM_W / (float)DET_TOTAL;          // mean over B,S,17,H,W
    const float tag_scale = TAG_W / (float)(B_ * S_);         // mean over B,S (tagdim=1)
    float total = det_acc * det_scale + tag_acc * tag_scale;

    // ---- block reduction: wave shfl + LDS across 4 waves ----
    for (int off = 32; off; off >>= 1)
        total += __shfl_down(total, off, 64);
    __shared__ float smem[4];
    int lane = threadIdx.x & 63, wave = threadIdx.x >> 6;
    if (lane == 0) smem[wave] = total;
    __syncthreads();
    if (threadIdx.x == 0) {
        float s = smem[0] + smem[1] + smem[2] + smem[3];
        atomicAdd(out, s);
    }
}

extern "C" void kernel_launch(void* const* d_in, const int* in_sizes, int n_in,
                              void* d_out, int out_size, void* d_ws, size_t ws_size,
                              hipStream_t stream) {
    const float* preds    = (const float*)d_in[0];
    const float* masks    = (const float*)d_in[1];
    const int*   kp_idx   = (const int*)d_in[2];
    const float* kp_vis   = (const float*)d_in[3];
    const float* gt_tags  = (const float*)d_in[4];
    const float* heatmaps = (const float*)d_in[5];
    float* out = (float*)d_out;

    hipMemsetAsync(out, 0, sizeof(float), stream);

    // 2048 blocks x 256 threads: ~17 float4 iters/thread over the det region
    loss_fused_kernel<<<2048, 256, 0, stream>>>(
        preds, masks, kp_idx, kp_vis, gt_tags, heatmaps, out);
}

// Round 2
// 376.735 us; speedup vs baseline: 1.0106x; 1.0106x over previous
//
#include <hip/hip_runtime.h>

// Problem constants (fixed by reference setup_inputs)
#define NPARTS 17
#define TAGDIM 1
#define B_ 32
#define S_ 4
#define M_ 30
#define HW_ 16384            // 128*128
#define C_ 34                // (1+TAGDIM)*NPARTS
#define TAG_W 0.001f
#define HM_W 1.0f

#define DET_PER_BS (NPARTS * HW_)                 // 278528 floats
#define DET_TOTAL  ((long)B_ * S_ * DET_PER_BS)   // 35,651,584
#define VPBS       (DET_PER_BS / 4)               // 69632 vec4 per (b,s)
#define VPBS_FULL  ((C_ * HW_) / 4)               // 139264 vec4 stride of full (b,s) slab
#define HV         (HW_ / 4)                      // 4096 vec4 per image plane
#define TAG_TOTAL  (B_ * S_ * M_ * NPARTS)        // 65280

#define CHUNKS     16                              // blocks per (b,s)
#define ITERS      17                              // VPBS / (CHUNKS*256) = 17
#define BS_COUNT   (B_ * S_)                       // 128

__global__ __launch_bounds__(256) void loss_fused_kernel(
    const float* __restrict__ preds,      // (B,S,34,H,W)
    const float* __restrict__ masks,      // (B,H,W)
    const int*   __restrict__ kp_idx,     // (B,M,17)
    const float* __restrict__ kp_vis,     // (B,M,17)
    const float* __restrict__ gt_tags,    // (B,1,M,17)
    const float* __restrict__ heatmaps,   // (B,17,H,W)
    float* __restrict__ out)
{
    const float4* __restrict__ preds4 = (const float4*)preds;
    const float4* __restrict__ masks4 = (const float4*)masks;
    const float4* __restrict__ heat4  = (const float4*)heatmaps;

    const int bs    = blockIdx.y;           // [0,128)
    const int b     = bs >> 2;              // S_ == 4
    const int tid   = threadIdx.x;

    // det region for this (b,s): 32-bit indexing throughout
    const float4* p4 = preds4 + (long)bs * VPBS_FULL;   // det half starts at slab base
    const float4* h4 = heat4  + b * VPBS;
    const float4* m4 = masks4 + b * HV;

    float det_acc = 0.f;
    int wv = blockIdx.x * (CHUNKS == 16 ? ITERS * 256 : 0) + tid;  // chunk base + lane
#pragma unroll
    for (int i = 0; i < ITERS; ++i, wv += 256) {
        float4 p = p4[wv];
        float4 h = h4[wv];
        float4 m = m4[wv & (HV - 1)];
        float dx = p.x - h.x, dy = p.y - h.y, dz = p.z - h.z, dw = p.w - h.w;
        det_acc += dx * dx * m.x + dy * dy * m.y + dz * dz * m.z + dw * dw * m.w;
    }

    // ---- tag loss: 65280 gathered elements, spread over all threads ----
    float tag_acc = 0.f;
    const int gtid = (blockIdx.y * gridDim.x + blockIdx.x) * 256 + tid;
    const int nthreads = gridDim.x * gridDim.y * 256;
    for (int t = gtid; t < TAG_TOTAL; t += nthreads) {
        int tbs = t / (M_ * NPARTS);             // [0,128)  (compile-time const divisor, 32-bit)
        int mp  = t - tbs * (M_ * NPARTS);
        int tb  = tbs >> 2;
        int gidx = tb * (M_ * NPARTS) + mp;
        int l    = kp_idx[gidx];                 // [0, 17*HW)
        float vis = kp_vis[gidx];
        float gt  = gt_tags[gidx];               // TAGDIM==1 -> flat (B,M,P)
        float pt  = preds[((long)tbs * C_ + NPARTS) * HW_ + l];
        float d = pt - gt;
        tag_acc += d * d * vis;
    }

    const float det_scale = HM_W / (float)DET_TOTAL;   // mean over B,S,17,H,W
    const float tag_scale = TAG_W / (float)(B_ * S_);  // mean over B,S (tagdim=1)
    float total = det_acc * det_scale + tag_acc * tag_scale;

    // ---- block reduction: wave shfl + LDS across 4 waves ----
    for (int off = 32; off; off >>= 1)
        total += __shfl_down(total, off, 64);
    __shared__ float smem[4];
    int lane = tid & 63, wave = tid >> 6;
    if (lane == 0) smem[wave] = total;
    __syncthreads();
    if (tid == 0) {
        float s = smem[0] + smem[1] + smem[2] + smem[3];
        atomicAdd(out, s);
    }
}

extern "C" void kernel_launch(void* const* d_in, const int* in_sizes, int n_in,
                              void* d_out, int out_size, void* d_ws, size_t ws_size,
                              hipStream_t stream) {
    const float* preds    = (const float*)d_in[0];
    const float* masks    = (const float*)d_in[1];
    const int*   kp_idx   = (const int*)d_in[2];
    const float* kp_vis   = (const float*)d_in[3];
    const float* gt_tags  = (const float*)d_in[4];
    const float* heatmaps = (const float*)d_in[5];
    float* out = (float*)d_out;

    hipMemsetAsync(out, 0, sizeof(float), stream);

    // grid: 16 chunks x 128 (b,s) slabs = 2048 blocks, 256 threads,
    // 17 float4 iters/thread, all 32-bit indexing (no div in hot loop)
    dim3 grid(CHUNKS, BS_COUNT);
    loss_fused_kernel<<<grid, 256, 0, stream>>>(
        preds, masks, kp_idx, kp_vis, gt_tags, heatmaps, out);
}